// Round 12
// baseline (295.597 us; speedup 1.0000x reference)
//
#include <hip/hip_runtime.h>
#include <hip/hip_bf16.h>
#include <stdint.h>

#define EPS 1e-5f
#define KPAD 136   // 128 k + 8 pad (f16) -> 272B row stride
#define NB 256     // max dst buckets
#define BSH 9      // 512 nodes per bucket
#define EB 4096    // edges per scatter block
#define MAXBLK 2048  // max scatter blocks supported by fill3 LDS (E <= 8.4M)

typedef __attribute__((ext_vector_type(4))) float f32x4;
typedef _Float16 f16;
typedef __attribute__((ext_vector_type(2))) _Float16 f16x2;
typedef __attribute__((ext_vector_type(8))) _Float16 f16x8;

__device__ __forceinline__ int rfl(int x) { return __builtin_amdgcn_readfirstlane(x); }
__device__ __forceinline__ float rflf(float x) {
    return __int_as_float(__builtin_amdgcn_readfirstlane(__float_as_int(x)));
}

// int64 detection: little-endian int64 with values < 2^31 => odd 32-bit words zero
__device__ __forceinline__ bool detect64(const uint32_t* w) {
    int lane = threadIdx.x & 63;
    uint32_t odd = w[1 + 2 * lane] | w[129 + 2 * lane];
    return !__any(odd != 0u);
}

// ---------------- scatter: block-sorted dense pair output ----------------
// Pack: (local_dst << 23) | src  -- requires src < 2^23, local_dst < 512.
__global__ __launch_bounds__(256) void k_scatter(const void* __restrict__ eidx,
                                                 uint32_t* __restrict__ staged,
                                                 int* __restrict__ cntmat,
                                                 int* __restrict__ offmat, int E) {
    __shared__ uint32_t sst[EB];
    __shared__ int hist[NB];
    __shared__ int off[NB];
    __shared__ int cur[NB];
    __shared__ int wsum[4], wexcl[4];
    bool is64 = detect64((const uint32_t*)eidx);
    int t = threadIdx.x, lane = t & 63, wv = t >> 6;
    hist[t] = 0;
    __syncthreads();
    int e0 = blockIdx.x * EB + t * 16;
    int s[16], d[16];
    #pragma unroll
    for (int i = 0; i < 16; i++) {
        int e = e0 + i;
        if (e < E) {
            if (is64) {
                const long long* p = (const long long*)eidx;
                s[i] = (int)p[e];
                d[i] = (int)p[(size_t)E + e];
            } else {
                const int* p = (const int*)eidx;
                s[i] = p[e];
                d[i] = p[(size_t)E + e];
            }
            atomicAdd(&hist[d[i] >> BSH], 1);
        }
    }
    __syncthreads();
    // block exclusive scan of hist[256]
    int v = hist[t];
    int incl = v;
    #pragma unroll
    for (int o = 1; o < 64; o <<= 1) {
        int tv = __shfl_up(incl, o);
        if (lane >= o) incl += tv;
    }
    if (lane == 63) wsum[wv] = incl;
    __syncthreads();
    if (t == 0) {
        int r = 0;
        #pragma unroll
        for (int i = 0; i < 4; i++) { wexcl[i] = r; r += wsum[i]; }
    }
    __syncthreads();
    int ex = incl - v + wexcl[wv];
    off[t] = ex;
    cur[t] = ex;
    __syncthreads();
    #pragma unroll
    for (int i = 0; i < 16; i++) {
        int e = e0 + i;
        if (e < E) {
            int b = d[i] >> BSH;
            int pos = atomicAdd(&cur[b], 1);
            sst[pos] = ((uint32_t)(d[i] - (b << BSH)) << 23) | (uint32_t)s[i];
        }
    }
    __syncthreads();
    int tot = E - blockIdx.x * EB;
    if (tot > EB) tot = EB;
    uint32_t* gp = staged + (size_t)blockIdx.x * EB;
    for (int i = t; i < tot; i += 256) gp[i] = sst[i];
    cntmat[blockIdx.x * NB + t] = hist[t];
    offmat[blockIdx.x * NB + t] = off[t];
}

// ---------------- bucket totals + global bases (1 block) ----------------
__global__ __launch_bounds__(256) void k_bsum(const int* __restrict__ cntmat,
                                              int* __restrict__ bbase, int nblk) {
    __shared__ int wsum[4], wexcl[4];
    int t = threadIdx.x, lane = t & 63, wv = t >> 6;
    int s = 0;
    for (int k = 0; k < nblk; k++) s += cntmat[k * NB + t];
    int incl = s;
    #pragma unroll
    for (int o = 1; o < 64; o <<= 1) {
        int tv = __shfl_up(incl, o);
        if (lane >= o) incl += tv;
    }
    if (lane == 63) wsum[wv] = incl;
    __syncthreads();
    if (t == 0) {
        int r = 0;
        #pragma unroll
        for (int i = 0; i < 4; i++) { wexcl[i] = r; r += wsum[i]; }
    }
    __syncthreads();
    bbase[t] = incl - s + wexcl[wv];
}

// ---------------- per-bucket CSR build from segmented sorted pairs ----------------
__global__ __launch_bounds__(256) void k_fill3(const uint32_t* __restrict__ staged,
                                               const int* __restrict__ cntmat,
                                               const int* __restrict__ offmat,
                                               const int* __restrict__ bbase,
                                               int* __restrict__ rowptr,
                                               float* __restrict__ dinv,
                                               int* __restrict__ adj,
                                               int N, int E, int nblk) {
    __shared__ int segstart[MAXBLK + 1];
    __shared__ int offk[MAXBLK];
    __shared__ int hist[512];
    __shared__ int wsum[4], wexcl[4];
    int b = blockIdx.x, t = threadIdx.x, lane = t & 63, wv = t >> 6;
    int d0 = b << BSH;
    int W = N - d0;
    if (W > 512) W = 512;

    // segment-start scan over scatter blocks (chunks of 256 with carry)
    int carry = 0;
    for (int cb = 0; cb < nblk; cb += 256) {
        int k = cb + t;
        int v = (k < nblk) ? cntmat[k * NB + b] : 0;
        int ok = (k < nblk) ? offmat[k * NB + b] : 0;
        int incl = v;
        #pragma unroll
        for (int o = 1; o < 64; o <<= 1) {
            int tv = __shfl_up(incl, o);
            if (lane >= o) incl += tv;
        }
        if (lane == 63) wsum[wv] = incl;
        __syncthreads();
        if (t == 0) {
            int r = 0;
            #pragma unroll
            for (int i = 0; i < 4; i++) { wexcl[i] = r; r += wsum[i]; }
        }
        __syncthreads();
        if (k < nblk) {
            segstart[k] = carry + incl - v + wexcl[wv];
            offk[k] = ok;
        }
        carry += wsum[0] + wsum[1] + wsum[2] + wsum[3];
        __syncthreads();
    }
    if (t == 0) segstart[nblk] = carry;
    hist[t] = 0;
    hist[t + 256] = 0;
    __syncthreads();
    int n = segstart[nblk];
    int base = bbase[b];

    // phase 1: degree histogram (binary search into segments)
    for (int i = t; i < n; i += 256) {
        int lo = 0, hi = nblk;
        while (hi - lo > 1) {
            int mid = (lo + hi) >> 1;
            if (segstart[mid] <= i) lo = mid; else hi = mid;
        }
        uint32_t u = staged[(size_t)lo * EB + offk[lo] + (i - segstart[lo])];
        atomicAdd(&hist[u >> 23], 1);
    }
    __syncthreads();
    // phase 2: block exclusive scan of 512 counters (2/thread)
    int i0 = 2 * t, i1 = 2 * t + 1;
    int a = hist[i0], bv = hist[i1];
    int s2 = a + bv;
    int incl = s2;
    #pragma unroll
    for (int o = 1; o < 64; o <<= 1) {
        int tv = __shfl_up(incl, o);
        if (lane >= o) incl += tv;
    }
    if (lane == 63) wsum[wv] = incl;
    __syncthreads();
    if (t == 0) {
        int r = 0;
        #pragma unroll
        for (int i = 0; i < 4; i++) { wexcl[i] = r; r += wsum[i]; }
    }
    __syncthreads();
    int excl = incl - s2 + wexcl[wv];
    if (i0 < W) {
        rowptr[d0 + i0] = base + excl;
        dinv[d0 + i0] = rsqrtf((float)(a + 1));
    }
    if (i1 < W) {
        rowptr[d0 + i1] = base + excl + a;
        dinv[d0 + i1] = rsqrtf((float)(bv + 1));
    }
    if (b == gridDim.x - 1 && t == 0) rowptr[N] = E;
    __syncthreads();
    hist[i0] = excl;
    hist[i1] = excl + a;
    __syncthreads();
    // phase 3: place edges
    for (int i = t; i < n; i += 256) {
        int lo = 0, hi = nblk;
        while (hi - lo > 1) {
            int mid = (lo + hi) >> 1;
            if (segstart[mid] <= i) lo = mid; else hi = mid;
        }
        uint32_t u = staged[(size_t)lo * EB + offk[lo] + (i - segstart[lo])];
        int pos = atomicAdd(&hist[u >> 23], 1);
        adj[base + pos] = (int)(u & 0x7fffffu);
    }
}

// ---------------- W -> transposed padded f16 hi/lo ----------------
__global__ void k_wconv(const float* __restrict__ W0, const float* __restrict__ W1,
                        const float* __restrict__ W2, f16* __restrict__ T0,
                        f16* __restrict__ T1, f16* __restrict__ T2) {
    int layer = blockIdx.y;
    const float* W = layer == 0 ? W0 : (layer == 1 ? W1 : W2);
    f16* T = layer == 0 ? T0 : (layer == 1 ? T1 : T2);
    int outc = (layer == 2) ? 64 : 128;
    int tid = blockIdx.x * 256 + threadIdx.x;
    if (tid >= 128 * outc) return;
    int k = tid / outc, c = tid % outc;
    float f = W[tid];
    f16 hb = (f16)f;
    f16 lb = (f16)(f - (float)hb);
    T[c * KPAD + k] = hb;
    T[outc * KPAD + c * KPAD + k] = lb;
}

// ---------------- MFMA GEMM: C[N x OUTC](f16) = dinv .* (A[N x 128] @ W) ----------------
template <int OUTC, typename AT>
__global__ __launch_bounds__(256, OUTC == 64 ? 4 : 2)
void k_gemm_mfma(const AT* __restrict__ A, const f16* __restrict__ WT,
                 const float* __restrict__ dinv, f16* __restrict__ C, int N) {
    __shared__ f16 lds[2 * OUTC * KPAD];
    const int t = threadIdx.x;
    const int n16 = (2 * OUTC * KPAD * 2) / 16;
    for (int i = t; i < n16; i += 256)
        ((float4*)lds)[i] = ((const float4*)WT)[i];

    const int lane = t & 63;
    const int wv = t >> 6;
    const int c = lane & 15;
    const int hq = lane >> 4;
    const int rowbase = blockIdx.x * 128 + wv * 32;

    constexpr bool IS16 = (sizeof(AT) == 2);
    f16x8 ahi[2][4], alo[2][4];
    #pragma unroll
    for (int rt = 0; rt < 2; ++rt) {
        int ar = rowbase + rt * 16 + c;
        if (ar > N - 1) ar = N - 1;
        const AT* ap = A + (size_t)ar * 128 + hq * 8;
        #pragma unroll
        for (int ks = 0; ks < 4; ++ks) {
            if constexpr (IS16) {
                ahi[rt][ks] = *(const f16x8*)(ap + ks * 32);
            } else {
                float4 p = *(const float4*)(ap + ks * 32);
                float4 q = *(const float4*)(ap + ks * 32 + 4);
                float v[8] = {p.x, p.y, p.z, p.w, q.x, q.y, q.z, q.w};
                #pragma unroll
                for (int j = 0; j < 8; ++j) {
                    f16 hb = (f16)v[j];
                    ahi[rt][ks][j] = hb;
                    alo[rt][ks][j] = (f16)(v[j] - (float)hb);
                }
            }
        }
    }
    float di[2][4];
    #pragma unroll
    for (int rt = 0; rt < 2; ++rt)
        #pragma unroll
        for (int r = 0; r < 4; ++r) {
            int row = rowbase + rt * 16 + hq * 4 + r;
            di[rt][r] = (row < N) ? dinv[row] : 0.f;
        }
    __syncthreads();

    #pragma unroll
    for (int ct = 0; ct < OUTC / 16; ++ct) {
        const f16* bp = &lds[(ct * 16 + c) * KPAD + hq * 8];
        f16x8 bhi[4], blo[4];
        #pragma unroll
        for (int ks = 0; ks < 4; ++ks) {
            bhi[ks] = *reinterpret_cast<const f16x8*>(bp + ks * 32);
            blo[ks] = *reinterpret_cast<const f16x8*>(bp + OUTC * KPAD + ks * 32);
        }
        f32x4 acc0 = {0.f, 0.f, 0.f, 0.f};
        f32x4 acc1 = {0.f, 0.f, 0.f, 0.f};
        #pragma unroll
        for (int ks = 0; ks < 4; ++ks) {
            acc0 = __builtin_amdgcn_mfma_f32_16x16x32_f16(ahi[0][ks], bhi[ks], acc0, 0, 0, 0);
            acc1 = __builtin_amdgcn_mfma_f32_16x16x32_f16(ahi[1][ks], bhi[ks], acc1, 0, 0, 0);
            if constexpr (!IS16) {
                acc0 = __builtin_amdgcn_mfma_f32_16x16x32_f16(alo[0][ks], bhi[ks], acc0, 0, 0, 0);
                acc1 = __builtin_amdgcn_mfma_f32_16x16x32_f16(alo[1][ks], bhi[ks], acc1, 0, 0, 0);
            }
            acc0 = __builtin_amdgcn_mfma_f32_16x16x32_f16(ahi[0][ks], blo[ks], acc0, 0, 0, 0);
            acc1 = __builtin_amdgcn_mfma_f32_16x16x32_f16(ahi[1][ks], blo[ks], acc1, 0, 0, 0);
        }
        const int col = ct * 16 + c;
        #pragma unroll
        for (int rt = 0; rt < 2; ++rt) {
            f32x4 a = rt ? acc1 : acc0;
            int row0 = rowbase + rt * 16 + hq * 4;
            #pragma unroll
            for (int r = 0; r < 4; ++r) {
                int row = row0 + r;
                if (row < N) C[(size_t)row * OUTC + col] = (f16)(a[r] * di[rt][r]);
            }
        }
    }
}

// ---------------- aggregation + LayerNorm + ReLU (128 cols f16, 1 wave/node) ----------------
__global__ __launch_bounds__(256) void k_agg_ln(const f16* __restrict__ h,
                                                const int* __restrict__ rowptr,
                                                const int* __restrict__ adj,
                                                const float* __restrict__ dinv,
                                                const float* __restrict__ bias,
                                                const float* __restrict__ g,
                                                const float* __restrict__ bn,
                                                f16* __restrict__ out, int N) {
    int lane = threadIdx.x & 63;
    int v = rfl(blockIdx.x * 4 + (threadIdx.x >> 6));
    if (v >= N) return;
    int c = lane * 2;
    float dv = rflf(dinv[v]);
    f16x2 hv = *(const f16x2*)&h[(size_t)v * 128 + c];
    float ax = (float)hv[0];
    float ay = (float)hv[1];
    int e0 = rfl(rowptr[v]);
    int e1 = rfl(rowptr[v + 1]);
    int e = e0;
    for (; e + 16 <= e1; e += 16) {
        const f16* rp[16];
        #pragma unroll
        for (int i = 0; i < 16; i++) rp[i] = h + (size_t)rfl(adj[e + i]) * 128;
        f16x2 hh[16];
        #pragma unroll
        for (int i = 0; i < 16; i++) hh[i] = *(const f16x2*)&rp[i][c];
        #pragma unroll
        for (int i = 0; i < 16; i++) { ax += (float)hh[i][0]; ay += (float)hh[i][1]; }
    }
    for (; e + 4 <= e1; e += 4) {
        const f16* rp[4];
        #pragma unroll
        for (int i = 0; i < 4; i++) rp[i] = h + (size_t)rfl(adj[e + i]) * 128;
        f16x2 hh[4];
        #pragma unroll
        for (int i = 0; i < 4; i++) hh[i] = *(const f16x2*)&rp[i][c];
        #pragma unroll
        for (int i = 0; i < 4; i++) { ax += (float)hh[i][0]; ay += (float)hh[i][1]; }
    }
    for (; e < e1; e++) {
        const f16* rp = h + (size_t)rfl(adj[e]) * 128;
        f16x2 hu = *(const f16x2*)&rp[c];
        ax += (float)hu[0];
        ay += (float)hu[1];
    }
    float2 bb = *(const float2*)&bias[c];
    float px = fmaf(dv, ax, bb.x);
    float py = fmaf(dv, ay, bb.y);
    float s = px + py;
    #pragma unroll
    for (int m = 32; m >= 1; m >>= 1) s += __shfl_xor(s, m);
    float mu = s * (1.0f / 128.0f);
    float dx = px - mu, dy = py - mu;
    float vs = dx * dx + dy * dy;
    #pragma unroll
    for (int m = 32; m >= 1; m >>= 1) vs += __shfl_xor(vs, m);
    float rs = rsqrtf(vs * (1.0f / 128.0f) + EPS);
    float2 gg = *(const float2*)&g[c];
    float2 bnv = *(const float2*)&bn[c];
    float ox = fmaxf(dx * rs * gg.x + bnv.x, 0.0f);
    float oy = fmaxf(dy * rs * gg.y + bnv.y, 0.0f);
    f16x2 o;
    o[0] = (f16)ox;
    o[1] = (f16)oy;
    *(f16x2*)&out[(size_t)v * 128 + c] = o;
}

// ---------------- aggregation + bias (64 cols f16 in, f32 out; 1 col/lane) ----------------
__global__ __launch_bounds__(256) void k_agg_out(const f16* __restrict__ h,
                                                 const int* __restrict__ rowptr,
                                                 const int* __restrict__ adj,
                                                 const float* __restrict__ dinv,
                                                 const float* __restrict__ bias,
                                                 float* __restrict__ out, int N) {
    int lane = threadIdx.x & 63;
    int v = rfl(blockIdx.x * 4 + (threadIdx.x >> 6));
    if (v >= N) return;
    float dv = rflf(dinv[v]);
    float acc = (float)h[(size_t)v * 64 + lane];
    int e0 = rfl(rowptr[v]);
    int e1 = rfl(rowptr[v + 1]);
    int e = e0;
    for (; e + 16 <= e1; e += 16) {
        const f16* rp[16];
        #pragma unroll
        for (int i = 0; i < 16; i++) rp[i] = h + (size_t)rfl(adj[e + i]) * 64;
        f16 hh[16];
        #pragma unroll
        for (int i = 0; i < 16; i++) hh[i] = rp[i][lane];
        #pragma unroll
        for (int i = 0; i < 16; i++) acc += (float)hh[i];
    }
    for (; e + 4 <= e1; e += 4) {
        const f16* rp[4];
        #pragma unroll
        for (int i = 0; i < 4; i++) rp[i] = h + (size_t)rfl(adj[e + i]) * 64;
        f16 hh[4];
        #pragma unroll
        for (int i = 0; i < 4; i++) hh[i] = rp[i][lane];
        #pragma unroll
        for (int i = 0; i < 4; i++) acc += (float)hh[i];
    }
    for (; e < e1; e++) {
        acc += (float)h[(size_t)rfl(adj[e]) * 64 + lane];
    }
    out[(size_t)v * 64 + lane] = fmaf(dv, acc, bias[lane]);
}

extern "C" void kernel_launch(void* const* d_in, const int* in_sizes, int n_in,
                              void* d_out, int out_size, void* d_ws, size_t ws_size,
                              hipStream_t stream) {
    const float* x    = (const float*)d_in[0];
    const void*  eidx = d_in[1];
    const float* W0 = (const float*)d_in[2];
    const float* b0 = (const float*)d_in[3];
    const float* W1 = (const float*)d_in[4];
    const float* b1 = (const float*)d_in[5];
    const float* W2 = (const float*)d_in[6];
    const float* b2 = (const float*)d_in[7];
    const float* g0 = (const float*)d_in[8];
    const float* bn0 = (const float*)d_in[9];
    const float* g1 = (const float*)d_in[10];
    const float* bn1 = (const float*)d_in[11];

    int N = in_sizes[0] / 128;
    int E = in_sizes[1] / 2;

    int used = ((N - 1) >> BSH) + 1;      // dst buckets (<=256 for N<=131072)
    int nblk = (E + EB - 1) / EB;         // scatter blocks (<=MAXBLK for E<=8.4M)

    char* p = (char*)d_ws;
    auto alloc = [&](size_t bytes) {
        char* r = p;
        p += (bytes + 255) & ~(size_t)255;
        return r;
    };
    int*      rowptr = (int*)alloc(((size_t)N + 1) * 4);
    float*    dinv   = (float*)alloc((size_t)N * 4);
    int*      adj    = (int*)alloc((size_t)E * 4);
    uint32_t* staged = (uint32_t*)alloc((size_t)nblk * EB * 4);
    int*      cntmat = (int*)alloc((size_t)nblk * NB * 4);
    int*      offmat = (int*)alloc((size_t)nblk * NB * 4);
    int*      bbase  = (int*)alloc(NB * 4);
    f16*      wt0    = (f16*)alloc(2 * 128 * KPAD * 2);
    f16*      wt1    = (f16*)alloc(2 * 128 * KPAD * 2);
    f16*      wt2    = (f16*)alloc(2 * 64 * KPAD * 2);
    f16*      bufA   = (f16*)alloc((size_t)N * 128 * 2);
    f16*      bufB   = (f16*)alloc((size_t)N * 128 * 2);

    k_wconv<<<dim3(64, 3), 256, 0, stream>>>(W0, W1, W2, wt0, wt1, wt2);
    k_scatter<<<nblk, 256, 0, stream>>>(eidx, staged, cntmat, offmat, E);
    k_bsum<<<1, 256, 0, stream>>>(cntmat, bbase, nblk);
    k_fill3<<<used, 256, 0, stream>>>(staged, cntmat, offmat, bbase, rowptr, dinv, adj, N, E, nblk);

    int gemmb = (N + 127) / 128;
    int aggb = (N + 3) / 4;

    k_gemm_mfma<128, float><<<gemmb, 256, 0, stream>>>(x, wt0, dinv, bufA, N);
    k_agg_ln<<<aggb, 256, 0, stream>>>(bufA, rowptr, adj, dinv, b0, g0, bn0, bufB, N);
    k_gemm_mfma<128, f16><<<gemmb, 256, 0, stream>>>(bufB, wt1, dinv, bufA, N);
    k_agg_ln<<<aggb, 256, 0, stream>>>(bufA, rowptr, adj, dinv, b1, g1, bn1, bufB, N);
    k_gemm_mfma<64, f16><<<gemmb, 256, 0, stream>>>(bufB, wt2, dinv, bufA, N);
    k_agg_out<<<aggb, 256, 0, stream>>>(bufA, rowptr, adj, dinv, b2, (float*)d_out, N);
}

// Round 13
// 252.650 us; speedup vs baseline: 1.1700x; 1.1700x over previous
//
#include <hip/hip_runtime.h>
#include <hip/hip_bf16.h>
#include <stdint.h>

#define EPS 1e-5f
#define KPAD 136   // 128 k + 8 pad (f16) -> 272B row stride
#define NB 256     // max dst buckets
#define BSH 9      // bucket shift: 512 nodes per bucket

typedef __attribute__((ext_vector_type(4))) float f32x4;
typedef _Float16 f16;
typedef __attribute__((ext_vector_type(2))) _Float16 f16x2;
typedef __attribute__((ext_vector_type(8))) _Float16 f16x8;

__device__ __forceinline__ int rfl(int x) { return __builtin_amdgcn_readfirstlane(x); }
__device__ __forceinline__ float rflf(float x) {
    return __int_as_float(__builtin_amdgcn_readfirstlane(__float_as_int(x)));
}

// int64 detection: little-endian int64 with values < 2^31 => odd 32-bit words zero
__device__ __forceinline__ bool detect64(const uint32_t* w) {
    int lane = threadIdx.x & 63;
    uint32_t odd = w[1 + 2 * lane] | w[129 + 2 * lane];
    return !__any(odd != 0u);
}

// ---------------- bucket scatter (slab, round-9 form) ----------------
__global__ __launch_bounds__(256) void k_scatter(const void* __restrict__ eidx,
                                                 int* __restrict__ bcount,
                                                 int2* __restrict__ bpairs,
                                                 int E, int cap) {
    __shared__ int hist[NB];
    __shared__ int base[NB];
    bool is64 = detect64((const uint32_t*)eidx);
    int t = threadIdx.x;
    if (t < NB) hist[t] = 0;
    __syncthreads();
    int e0 = blockIdx.x * 2048 + t * 8;
    int s[8], d[8], b[8], rank[8];
    #pragma unroll
    for (int i = 0; i < 8; i++) {
        int e = e0 + i;
        if (e < E) {
            if (is64) {
                const long long* p = (const long long*)eidx;
                s[i] = (int)p[e];
                d[i] = (int)p[(size_t)E + e];
            } else {
                const int* p = (const int*)eidx;
                s[i] = p[e];
                d[i] = p[(size_t)E + e];
            }
            b[i] = d[i] >> BSH;
            rank[i] = atomicAdd(&hist[b[i]], 1);
        }
    }
    __syncthreads();
    if (t < NB) base[t] = hist[t] ? atomicAdd(&bcount[t], hist[t]) : 0;
    __syncthreads();
    #pragma unroll
    for (int i = 0; i < 8; i++) {
        int e = e0 + i;
        if (e < E) {
            int idx = base[b[i]] + rank[i];
            if (idx < cap) bpairs[(size_t)b[i] * cap + idx] = make_int2(s[i], d[i]);
        }
    }
}

// ---------------- exclusive scan of bucket counts (1 wave) ----------------
__global__ void k_bscan(const int* __restrict__ bcount, int* __restrict__ bbase, int used) {
    int lane = threadIdx.x;
    int carry = 0;
    for (int base = 0; base < used; base += 64) {
        int i = base + lane;
        int v = (i < used) ? bcount[i] : 0;
        int orig = v;
        #pragma unroll
        for (int off = 1; off < 64; off <<= 1) {
            int t = __shfl_up(v, off);
            if (lane >= off) v += t;
        }
        if (i < used) bbase[i] = carry + v - orig;
        carry += __shfl(v, 63);
    }
}

// ---------------- per-bucket CSR build (round-9 form) ----------------
__global__ __launch_bounds__(256) void k_fill3(const int2* __restrict__ bpairs,
                                               const int* __restrict__ bcount,
                                               const int* __restrict__ bbase,
                                               int* __restrict__ rowptr,
                                               float* __restrict__ dinv,
                                               int* __restrict__ adj,
                                               int N, int E, int cap) {
    __shared__ int hist[512];
    __shared__ int wsum[4];
    __shared__ int wexcl[4];
    int b = blockIdx.x;
    int t = threadIdx.x;
    int lane = t & 63;
    int wv = t >> 6;
    int d0 = b << BSH;
    int W = N - d0;
    if (W > 512) W = 512;
    int n = bcount[b];
    if (n > cap) n = cap;
    int base = bbase[b];
    const int2* p = bpairs + (size_t)b * cap;

    hist[t] = 0;
    hist[t + 256] = 0;
    __syncthreads();
    for (int i = t; i < n; i += 256) atomicAdd(&hist[p[i].y - d0], 1);
    __syncthreads();
    int i0 = 2 * t, i1 = 2 * t + 1;
    int a = hist[i0], bv = hist[i1];
    int s2 = a + bv;
    int incl = s2;
    #pragma unroll
    for (int off = 1; off < 64; off <<= 1) {
        int tv = __shfl_up(incl, off);
        if (lane >= off) incl += tv;
    }
    if (lane == 63) wsum[wv] = incl;
    __syncthreads();
    if (t == 0) {
        int r = 0;
        #pragma unroll
        for (int i = 0; i < 4; i++) { wexcl[i] = r; r += wsum[i]; }
    }
    __syncthreads();
    int excl = incl - s2 + wexcl[wv];
    if (i0 < W) {
        rowptr[d0 + i0] = base + excl;
        dinv[d0 + i0] = rsqrtf((float)(a + 1));
    }
    if (i1 < W) {
        rowptr[d0 + i1] = base + excl + a;
        dinv[d0 + i1] = rsqrtf((float)(bv + 1));
    }
    if (b == gridDim.x - 1 && t == 0) rowptr[N] = E;
    __syncthreads();
    hist[i0] = excl;
    hist[i1] = excl + a;
    __syncthreads();
    for (int i = t; i < n; i += 256) {
        int2 pr = p[i];
        int pos = atomicAdd(&hist[pr.y - d0], 1);
        adj[base + pos] = pr.x;
    }
}

// ---------------- W -> transposed padded f16 hi/lo ----------------
__global__ void k_wconv(const float* __restrict__ W0, const float* __restrict__ W1,
                        const float* __restrict__ W2, f16* __restrict__ T0,
                        f16* __restrict__ T1, f16* __restrict__ T2) {
    int layer = blockIdx.y;
    const float* W = layer == 0 ? W0 : (layer == 1 ? W1 : W2);
    f16* T = layer == 0 ? T0 : (layer == 1 ? T1 : T2);
    int outc = (layer == 2) ? 64 : 128;
    int tid = blockIdx.x * 256 + threadIdx.x;
    if (tid >= 128 * outc) return;
    int k = tid / outc, c = tid % outc;
    float f = W[tid];
    f16 hb = (f16)f;
    f16 lb = (f16)(f - (float)hb);
    T[c * KPAD + k] = hb;
    T[outc * KPAD + c * KPAD + k] = lb;
}

// ---------------- MFMA GEMM: C[N x OUTC](f16) = dinv .* (A[N x 128] @ W) ----------------
// f16 A-path: raw f16 fragments, 2 MFMA/product. f32 A-path: f16 hi/lo, 3 MFMA.
template <int OUTC, typename AT>
__global__ __launch_bounds__(256, OUTC == 64 ? 4 : 2)
void k_gemm_mfma(const AT* __restrict__ A, const f16* __restrict__ WT,
                 const float* __restrict__ dinv, f16* __restrict__ C, int N) {
    __shared__ f16 lds[2 * OUTC * KPAD];
    const int t = threadIdx.x;
    const int n16 = (2 * OUTC * KPAD * 2) / 16;
    for (int i = t; i < n16; i += 256)
        ((float4*)lds)[i] = ((const float4*)WT)[i];

    const int lane = t & 63;
    const int wv = t >> 6;
    const int c = lane & 15;
    const int hq = lane >> 4;
    const int rowbase = blockIdx.x * 128 + wv * 32;

    constexpr bool IS16 = (sizeof(AT) == 2);
    f16x8 ahi[2][4], alo[2][4];
    #pragma unroll
    for (int rt = 0; rt < 2; ++rt) {
        int ar = rowbase + rt * 16 + c;
        if (ar > N - 1) ar = N - 1;
        const AT* ap = A + (size_t)ar * 128 + hq * 8;
        #pragma unroll
        for (int ks = 0; ks < 4; ++ks) {
            if constexpr (IS16) {
                ahi[rt][ks] = *(const f16x8*)(ap + ks * 32);
            } else {
                float4 p = *(const float4*)(ap + ks * 32);
                float4 q = *(const float4*)(ap + ks * 32 + 4);
                float v[8] = {p.x, p.y, p.z, p.w, q.x, q.y, q.z, q.w};
                #pragma unroll
                for (int j = 0; j < 8; ++j) {
                    f16 hb = (f16)v[j];
                    ahi[rt][ks][j] = hb;
                    alo[rt][ks][j] = (f16)(v[j] - (float)hb);
                }
            }
        }
    }
    float di[2][4];
    #pragma unroll
    for (int rt = 0; rt < 2; ++rt)
        #pragma unroll
        for (int r = 0; r < 4; ++r) {
            int row = rowbase + rt * 16 + hq * 4 + r;
            di[rt][r] = (row < N) ? dinv[row] : 0.f;
        }
    __syncthreads();

    #pragma unroll
    for (int ct = 0; ct < OUTC / 16; ++ct) {
        const f16* bp = &lds[(ct * 16 + c) * KPAD + hq * 8];
        f16x8 bhi[4], blo[4];
        #pragma unroll
        for (int ks = 0; ks < 4; ++ks) {
            bhi[ks] = *reinterpret_cast<const f16x8*>(bp + ks * 32);
            blo[ks] = *reinterpret_cast<const f16x8*>(bp + OUTC * KPAD + ks * 32);
        }
        f32x4 acc0 = {0.f, 0.f, 0.f, 0.f};
        f32x4 acc1 = {0.f, 0.f, 0.f, 0.f};
        #pragma unroll
        for (int ks = 0; ks < 4; ++ks) {
            acc0 = __builtin_amdgcn_mfma_f32_16x16x32_f16(ahi[0][ks], bhi[ks], acc0, 0, 0, 0);
            acc1 = __builtin_amdgcn_mfma_f32_16x16x32_f16(ahi[1][ks], bhi[ks], acc1, 0, 0, 0);
            if constexpr (!IS16) {
                acc0 = __builtin_amdgcn_mfma_f32_16x16x32_f16(alo[0][ks], bhi[ks], acc0, 0, 0, 0);
                acc1 = __builtin_amdgcn_mfma_f32_16x16x32_f16(alo[1][ks], bhi[ks], acc1, 0, 0, 0);
            }
            acc0 = __builtin_amdgcn_mfma_f32_16x16x32_f16(ahi[0][ks], blo[ks], acc0, 0, 0, 0);
            acc1 = __builtin_amdgcn_mfma_f32_16x16x32_f16(ahi[1][ks], blo[ks], acc1, 0, 0, 0);
        }
        const int col = ct * 16 + c;
        #pragma unroll
        for (int rt = 0; rt < 2; ++rt) {
            f32x4 a = rt ? acc1 : acc0;
            int row0 = rowbase + rt * 16 + hq * 4;
            #pragma unroll
            for (int r = 0; r < 4; ++r) {
                int row = row0 + r;
                if (row < N) C[(size_t)row * OUTC + col] = (f16)(a[r] * di[rt][r]);
            }
        }
    }
}

// ---------------- aggregation + LayerNorm + ReLU (128 cols f16, 1 wave/node) ----------------
__global__ __launch_bounds__(256) void k_agg_ln(const f16* __restrict__ h,
                                                const int* __restrict__ rowptr,
                                                const int* __restrict__ adj,
                                                const float* __restrict__ dinv,
                                                const float* __restrict__ bias,
                                                const float* __restrict__ g,
                                                const float* __restrict__ bn,
                                                f16* __restrict__ out, int N) {
    int lane = threadIdx.x & 63;
    int v = rfl(blockIdx.x * 4 + (threadIdx.x >> 6));
    if (v >= N) return;
    int c = lane * 2;
    float dv = rflf(dinv[v]);
    f16x2 hv = *(const f16x2*)&h[(size_t)v * 128 + c];
    float ax = (float)hv[0];
    float ay = (float)hv[1];
    int e0 = rfl(rowptr[v]);
    int e1 = rfl(rowptr[v + 1]);
    int e = e0;
    for (; e + 16 <= e1; e += 16) {
        const f16* rp[16];
        #pragma unroll
        for (int i = 0; i < 16; i++) rp[i] = h + (size_t)rfl(adj[e + i]) * 128;
        f16x2 hh[16];
        #pragma unroll
        for (int i = 0; i < 16; i++) hh[i] = *(const f16x2*)&rp[i][c];
        #pragma unroll
        for (int i = 0; i < 16; i++) { ax += (float)hh[i][0]; ay += (float)hh[i][1]; }
    }
    for (; e + 4 <= e1; e += 4) {
        const f16* rp[4];
        #pragma unroll
        for (int i = 0; i < 4; i++) rp[i] = h + (size_t)rfl(adj[e + i]) * 128;
        f16x2 hh[4];
        #pragma unroll
        for (int i = 0; i < 4; i++) hh[i] = *(const f16x2*)&rp[i][c];
        #pragma unroll
        for (int i = 0; i < 4; i++) { ax += (float)hh[i][0]; ay += (float)hh[i][1]; }
    }
    for (; e < e1; e++) {
        const f16* rp = h + (size_t)rfl(adj[e]) * 128;
        f16x2 hu = *(const f16x2*)&rp[c];
        ax += (float)hu[0];
        ay += (float)hu[1];
    }
    float2 bb = *(const float2*)&bias[c];
    float px = fmaf(dv, ax, bb.x);
    float py = fmaf(dv, ay, bb.y);
    float s = px + py;
    #pragma unroll
    for (int m = 32; m >= 1; m >>= 1) s += __shfl_xor(s, m);
    float mu = s * (1.0f / 128.0f);
    float dx = px - mu, dy = py - mu;
    float vs = dx * dx + dy * dy;
    #pragma unroll
    for (int m = 32; m >= 1; m >>= 1) vs += __shfl_xor(vs, m);
    float rs = rsqrtf(vs * (1.0f / 128.0f) + EPS);
    float2 gg = *(const float2*)&g[c];
    float2 bnv = *(const float2*)&bn[c];
    float ox = fmaxf(dx * rs * gg.x + bnv.x, 0.0f);
    float oy = fmaxf(dy * rs * gg.y + bnv.y, 0.0f);
    f16x2 o;
    o[0] = (f16)ox;
    o[1] = (f16)oy;
    *(f16x2*)&out[(size_t)v * 128 + c] = o;
}

// ---------------- aggregation + bias (64 cols f16 in, f32 out; 1 col/lane) ----------------
__global__ __launch_bounds__(256) void k_agg_out(const f16* __restrict__ h,
                                                 const int* __restrict__ rowptr,
                                                 const int* __restrict__ adj,
                                                 const float* __restrict__ dinv,
                                                 const float* __restrict__ bias,
                                                 float* __restrict__ out, int N) {
    int lane = threadIdx.x & 63;
    int v = rfl(blockIdx.x * 4 + (threadIdx.x >> 6));
    if (v >= N) return;
    float dv = rflf(dinv[v]);
    float acc = (float)h[(size_t)v * 64 + lane];
    int e0 = rfl(rowptr[v]);
    int e1 = rfl(rowptr[v + 1]);
    int e = e0;
    for (; e + 16 <= e1; e += 16) {
        const f16* rp[16];
        #pragma unroll
        for (int i = 0; i < 16; i++) rp[i] = h + (size_t)rfl(adj[e + i]) * 64;
        f16 hh[16];
        #pragma unroll
        for (int i = 0; i < 16; i++) hh[i] = rp[i][lane];
        #pragma unroll
        for (int i = 0; i < 16; i++) acc += (float)hh[i];
    }
    for (; e + 4 <= e1; e += 4) {
        const f16* rp[4];
        #pragma unroll
        for (int i = 0; i < 4; i++) rp[i] = h + (size_t)rfl(adj[e + i]) * 64;
        f16 hh[4];
        #pragma unroll
        for (int i = 0; i < 4; i++) hh[i] = rp[i][lane];
        #pragma unroll
        for (int i = 0; i < 4; i++) acc += (float)hh[i];
    }
    for (; e < e1; e++) {
        acc += (float)h[(size_t)rfl(adj[e]) * 64 + lane];
    }
    out[(size_t)v * 64 + lane] = fmaf(dv, acc, bias[lane]);
}

extern "C" void kernel_launch(void* const* d_in, const int* in_sizes, int n_in,
                              void* d_out, int out_size, void* d_ws, size_t ws_size,
                              hipStream_t stream) {
    const float* x    = (const float*)d_in[0];
    const void*  eidx = d_in[1];
    const float* W0 = (const float*)d_in[2];
    const float* b0 = (const float*)d_in[3];
    const float* W1 = (const float*)d_in[4];
    const float* b1 = (const float*)d_in[5];
    const float* W2 = (const float*)d_in[6];
    const float* b2 = (const float*)d_in[7];
    const float* g0 = (const float*)d_in[8];
    const float* bn0 = (const float*)d_in[9];
    const float* g1 = (const float*)d_in[10];
    const float* bn1 = (const float*)d_in[11];

    int N = in_sizes[0] / 128;
    int E = in_sizes[1] / 2;

    int used = ((N - 1) >> BSH) + 1;          // buckets of 512 nodes
    int cap = (E / used) * 2 + 256;           // slab capacity

    char* p = (char*)d_ws;
    auto alloc = [&](size_t bytes) {
        char* r = p;
        p += (bytes + 255) & ~(size_t)255;
        return r;
    };
    int*   rowptr  = (int*)alloc(((size_t)N + 1) * 4);
    float* dinv    = (float*)alloc((size_t)N * 4);
    int*   adj     = (int*)alloc((size_t)E * 4);
    int2*  bpairs  = (int2*)alloc((size_t)used * cap * 8);
    int*   bcount  = (int*)alloc(NB * 4);
    int*   bbase   = (int*)alloc(NB * 4);
    f16*   wt0     = (f16*)alloc(2 * 128 * KPAD * 2);
    f16*   wt1     = (f16*)alloc(2 * 128 * KPAD * 2);
    f16*   wt2     = (f16*)alloc(2 * 64 * KPAD * 2);
    f16*   bufA    = (f16*)alloc((size_t)N * 128 * 2);
    f16*   bufB    = (f16*)alloc((size_t)N * 128 * 2);

    int sb = (E + 2047) / 2048;

    hipMemsetAsync(bcount, 0, NB * 4, stream);
    k_wconv<<<dim3(64, 3), 256, 0, stream>>>(W0, W1, W2, wt0, wt1, wt2);
    k_scatter<<<sb, 256, 0, stream>>>(eidx, bcount, bpairs, E, cap);
    k_bscan<<<1, 64, 0, stream>>>(bcount, bbase, used);
    k_fill3<<<used, 256, 0, stream>>>(bpairs, bcount, bbase, rowptr, dinv, adj, N, E, cap);

    int gemmb = (N + 127) / 128;
    int aggb = (N + 3) / 4;

    k_gemm_mfma<128, float><<<gemmb, 256, 0, stream>>>(x, wt0, dinv, bufA, N);
    k_agg_ln<<<aggb, 256, 0, stream>>>(bufA, rowptr, adj, dinv, b0, g0, bn0, bufB, N);
    k_gemm_mfma<128, f16><<<gemmb, 256, 0, stream>>>(bufB, wt1, dinv, bufA, N);
    k_agg_ln<<<aggb, 256, 0, stream>>>(bufA, rowptr, adj, dinv, b1, g1, bn1, bufB, N);
    k_gemm_mfma<64, f16><<<gemmb, 256, 0, stream>>>(bufB, wt2, dinv, bufA, N);
    k_agg_out<<<aggb, 256, 0, stream>>>(bufA, rowptr, adj, dinv, b2, (float*)d_out, N);
}